// Round 5
// baseline (107.408 us; speedup 1.0000x reference)
//
#include <hip/hip_runtime.h>
#include <hip/hip_bf16.h>

#define DIM 1024
#define STATE 256
#define BATCH 4
#define SEQ 4096
#define M_TOT (BATCH * SEQ)  // 16384

typedef short short8 __attribute__((ext_vector_type(8)));
typedef float f32x4 __attribute__((ext_vector_type(4)));

__device__ __forceinline__ unsigned short f2bf(float f) {
  unsigned int u = __float_as_uint(f);
  u += 0x7fff + ((u >> 16) & 1);  // RNE
  return (unsigned short)(u >> 16);
}

__device__ __forceinline__ void gl_lds16(const void* g, void* l) {
  __builtin_amdgcn_global_load_lds(
      (const __attribute__((address_space(1))) void*)g,
      (__attribute__((address_space(3))) void*)l, 16, 0, 0);
}

#define C2F 2.8853900817779268f   // 2*log2(e)
#define LOG2EF 1.4426950408889634f
#define VMC(N) asm volatile("s_waitcnt vmcnt(" #N ")" ::: "memory")

// ---------------- convert ----------------------------------------------------
__global__ __launch_bounds__(256) void convert_kernel(
    const float* __restrict__ x, const float* __restrict__ A,
    const float* __restrict__ Bw, const float* __restrict__ Bb,
    const float* __restrict__ Cw, const float* __restrict__ Cb,
    const float* __restrict__ Dw, const float* __restrict__ Db,
    unsigned short* __restrict__ xb, unsigned short* __restrict__ bwb,
    unsigned short* __restrict__ wob, float* __restrict__ bb2,
    float* __restrict__ mP2, float* __restrict__ cbdb) {
  const int bx = blockIdx.x;
  const int t = threadIdx.x;
  if (bx < 16384) {                    // x: 16384*1024 floats, 4/thread
    size_t i = ((size_t)bx * 256 + t) * 4;
    const float4 v = *(const float4*)(x + i);
    *(ushort4*)(xb + i) = make_ushort4(f2bf(v.x), f2bf(v.y), f2bf(v.z), f2bf(v.w));
  } else if (bx < 16384 + 256) {       // bwb row per block
    int r = bx - 16384;
    int c = t * 4;
    const float4 v = *(const float4*)(Bw + (size_t)r * DIM + c);
    *(ushort4*)(bwb + (size_t)r * DIM + c) =
        make_ushort4(f2bf(v.x), f2bf(v.y), f2bf(v.z), f2bf(v.w));
  } else if (bx < 16384 + 256 + 1024) { // wob row e = [Cw[e,:] | Dw[e,:]]
    int e = bx - 16384 - 256;
    if (t < 64) {
      const float4 v = *(const float4*)(Cw + (size_t)e * STATE + t * 4);
      *(ushort4*)(wob + (size_t)e * 1280 + t * 4) =
          make_ushort4(f2bf(v.x), f2bf(v.y), f2bf(v.z), f2bf(v.w));
    }
    const float4 v = *(const float4*)(Dw + (size_t)e * DIM + t * 4);
    *(ushort4*)(wob + (size_t)e * 1280 + 256 + t * 4) =
        make_ushort4(f2bf(v.x), f2bf(v.y), f2bf(v.z), f2bf(v.w));
  } else {                             // scan constants + out bias, one block
    const float P = C2F * __builtin_amdgcn_exp2f(A[t] * LOG2EF);
    bb2[t] = fmaf(Bb[t], C2F, P);
    mP2[t] = -2.0f * P;
#pragma unroll
    for (int k = 0; k < 4; ++k) {
      const int i = t * 4 + k;
      cbdb[i] = Cb[i] + Db[i];
    }
  }
}

// ---------------- gemm_G: G = (x @ Bw^T)*C2 + bb2  (m97 128^2 structure) -----
__global__ __launch_bounds__(256, 2) void gemm_G(
    const unsigned short* __restrict__ A,  // xb [M][1024]
    const unsigned short* __restrict__ B,  // bwb [256][1024]
    float* __restrict__ G,                 // [M][256]
    const float* __restrict__ bb2) {
  __shared__ unsigned short As[128 * 32];
  __shared__ unsigned short Bs[128 * 32];

  const int tid = threadIdx.x;
  const int wave = tid >> 6;
  const int lane = tid & 63;
  const int lr = lane & 15;
  const int lk = lane >> 4;
  const int wr = wave >> 1;
  const int wc = wave & 1;

  const int ntile = blockIdx.x & 1;   // 2 n-tiles
  const int mtile = blockIdx.x >> 1;  // 128 m-tiles
  const int m0 = mtile * 128;
  const int n0 = ntile * 128;

  f32x4 acc[4][4];
#pragma unroll
  for (int i = 0; i < 4; ++i)
#pragma unroll
    for (int j = 0; j < 4; ++j) acc[i][j] = (f32x4){0.f, 0.f, 0.f, 0.f};

  const char* Abyte = (const char*)A;
  const char* Bbyte = (const char*)B;
  char* AsB = (char*)As;
  char* BsB = (char*)Bs;

  for (int k0 = 0; k0 < 1024; k0 += 32) {
#pragma unroll
    for (int i = 0; i < 2; ++i) {
      const int o = i * 4096 + tid * 16;
      const int r = o >> 6;
      const int cb = o & 63;
      gl_lds16(Abyte + (size_t)(m0 + r) * 2048 + (size_t)k0 * 2 + cb,
               AsB + i * 4096 + wave * 1024);
      gl_lds16(Bbyte + (size_t)(n0 + r) * 2048 + (size_t)k0 * 2 + cb,
               BsB + i * 4096 + wave * 1024);
    }
    __syncthreads();

    short8 af[4], bfr[4];
#pragma unroll
    for (int f = 0; f < 4; ++f) {
      af[f]  = *(const short8*)(AsB + (wr * 64 + f * 16 + lr) * 64 + lk * 16);
      bfr[f] = *(const short8*)(BsB + (wc * 64 + f * 16 + lr) * 64 + lk * 16);
    }
#pragma unroll
    for (int i = 0; i < 4; ++i)
#pragma unroll
      for (int j = 0; j < 4; ++j)
        acc[i][j] = __builtin_amdgcn_mfma_f32_16x16x32_bf16(af[i], bfr[j], acc[i][j], 0, 0, 0);
    __syncthreads();
  }

#pragma unroll
  for (int fi = 0; fi < 4; ++fi)
#pragma unroll
    for (int fj = 0; fj < 4; ++fj)
#pragma unroll
      for (int j = 0; j < 4; ++j) {
        const int rg = m0 + wr * 64 + fi * 16 + lk * 4 + j;
        const int cg = n0 + wc * 64 + fj * 16 + lr;
        G[(size_t)rg * STATE + cg] = fmaf(acc[fi][fj][j], C2F, bb2[cg]);
      }
}

// ---------------- chunked-parallel scan with warmup ---------------------------
// W=128: contraction |exp(A)(1-s^2)| ~0.85-0.95/step -> warmup error <~1.4e-3.
__global__ __launch_bounds__(256) void scan_kernel(
    const float* __restrict__ G, const float* __restrict__ mP2arr,
    unsigned short* __restrict__ states) {
  const int b = blockIdx.x >> 6;
  const int chunk = blockIdx.x & 63;
  const int n = threadIdx.x;
  const int t0 = chunk * 64;
  const int start = (t0 > 128) ? (t0 - 128) : 0;
  const int nw = t0 - start;
  const int total = nw + 64;

  const float* g = G + ((size_t)b * SEQ + start) * STATE + n;
  unsigned short* q = states + ((size_t)b * SEQ + start) * STATE + n;
  const float mP2 = mP2arr[n];

  float r = 0.5f;
  constexpr int CH = 16;
  float cur[CH], nxt[CH];
#pragma unroll
  for (int j = 0; j < CH; ++j) cur[j] = g[(size_t)j * STATE];

  const int NC = total / CH;
  for (int c = 0; c < NC; ++c) {
    if (c + 1 < NC) {
      const float* pn = g + (size_t)(c + 1) * CH * STATE;
#pragma unroll
      for (int j = 0; j < CH; ++j) nxt[j] = pn[(size_t)j * STATE];
    }
    if (c * CH >= nw) {
      unsigned short* qc = q + (size_t)c * CH * STATE;
#pragma unroll
      for (int j = 0; j < CH; ++j) {
        const float t = fmaf(mP2, r, cur[j]);
        const float e = __builtin_amdgcn_exp2f(t);
        r = __builtin_amdgcn_rcpf(1.0f + e);
        const float s = fmaf(-2.0f, r, 1.0f);
        qc[(size_t)j * STATE] = f2bf(s);
      }
    } else {
#pragma unroll
      for (int j = 0; j < CH; ++j) {
        const float t = fmaf(mP2, r, cur[j]);
        const float e = __builtin_amdgcn_exp2f(t);
        r = __builtin_amdgcn_rcpf(1.0f + e);
      }
    }
    if (c + 1 < NC) {
#pragma unroll
      for (int j = 0; j < CH; ++j) cur[j] = nxt[j];
    }
  }
}

// ---------------- gemm_out: dout = [states|x] @ [Cw|Dw]^T + (Cb+Db) ----------
// BM=128, BN=256, BK=32, K=1280 (40 tiles). Grid 512 = 2 blocks/CU (the whole
// point: cross-block LDS/MFMA overlap). 8 waves (2m x 4n), per-wave 64x64.
// LDS: 3-slot ring x (A 8KB + B 16KB) = 72KB -> 2 blocks/CU at <=128 VGPR.
// One barrier per K-tile; counted vmcnt(3) (3 loads/thread/tile, distance-2
// prefetch); drain only at tail. XOR chunk swizzle c^(r&3), source-side.
__global__ __launch_bounds__(512, 4) void gemm_out(
    const unsigned short* __restrict__ stb,  // [16384][256] bf16
    const unsigned short* __restrict__ xb,   // [16384][1024] bf16
    const unsigned short* __restrict__ wob,  // [1024][1280] bf16
    const float* __restrict__ cbdb,          // [1024]
    float* __restrict__ dout)                // [16384][1024] f32
{
  __shared__ char lds[73728];  // 3 slots x 24KB (A 8KB @0, B 16KB @8192)

  const int tid = threadIdx.x;
  const int wave = tid >> 6;
  const int lane = tid & 63;
  const int lr = lane & 15;
  const int lk = lane >> 4;
  const int wm = wave >> 2;  // 0..1
  const int wn = wave & 3;   // 0..3

  const int bs = ((blockIdx.x & 7) << 6) | (blockIdx.x >> 3);  // XCD swizzle (512%8==0)
  const int m0 = (bs >> 2) * 128;
  const int n0 = (bs & 3) * 256;

  const char* stbB = (const char*)stb;
  const char* xbB  = (const char*)xb;
  const char* wobB = (const char*)wob;

  f32x4 acc[4][4];
#pragma unroll
  for (int i = 0; i < 4; ++i)
#pragma unroll
    for (int j = 0; j < 4; ++j) acc[i][j] = (f32x4){0.f, 0.f, 0.f, 0.f};

  // stage one K-tile: A 128x64B (1 load/thread), B 256x64B (2 loads/thread)
  auto stage = [&](int kt) {
    if (kt >= 40) return;
    const int sl = kt % 3;
    {
      const char* base; size_t str; size_t colb;
      if (kt < 8) { base = stbB + (size_t)m0 * 512;  str = 512;  colb = (size_t)kt * 64; }
      else        { base = xbB  + (size_t)m0 * 2048; str = 2048; colb = (size_t)(kt - 8) * 64; }
      const int r = tid >> 2;
      const int c = (tid & 3) ^ (r & 3);
      gl_lds16(base + (size_t)r * str + colb + c * 16,
               lds + sl * 24576 + wave * 1024);
    }
#pragma unroll
    for (int i2 = 0; i2 < 2; ++i2) {
      const int s = i2 * 512 + tid;
      const int r = s >> 2;
      const int c = (s & 3) ^ (r & 3);
      gl_lds16(wobB + (size_t)(n0 + r) * 2560 + (size_t)kt * 64 + c * 16,
               lds + sl * 24576 + 8192 + i2 * 8192 + wave * 1024);
    }
  };

  // prologue
  stage(0); stage(1);
  VMC(3);  // stage(0) complete; stage(1) may fly
  __builtin_amdgcn_s_barrier();

  const int NT = 40;
  for (int t = 0; t < NT; ++t) {
    stage(t + 2);  // writes slot (t+2)%3 == (t-1)%3: safe, its readers passed
                   // the barrier at end of tile t-1 with reads consumed.
    const char* As = lds + (t % 3) * 24576;
    const char* Bs = As + 8192;

    short8 af[4], bfr[4];
#pragma unroll
    for (int f = 0; f < 4; ++f) {
      const int rb = wn * 64 + f * 16 + lr;
      bfr[f] = *(const short8*)(Bs + rb * 64 + ((lk ^ (rb & 3)) << 4));
      const int ra = wm * 64 + f * 16 + lr;
      af[f] = *(const short8*)(As + ra * 64 + ((lk ^ (ra & 3)) << 4));
    }
    __builtin_amdgcn_s_setprio(1);
#pragma unroll
    for (int fi = 0; fi < 4; ++fi)
#pragma unroll
      for (int fj = 0; fj < 4; ++fj)
        acc[fi][fj] = __builtin_amdgcn_mfma_f32_16x16x32_bf16(af[fi], bfr[fj], acc[fi][fj], 0, 0, 0);
    __builtin_amdgcn_s_setprio(0);

    if (t < NT - 2)       VMC(3);  // tile t+1's 3 loads complete (t+2's may fly)
    else if (t == NT - 2) VMC(0);  // tail: no stage(41) behind, full drain
    __builtin_amdgcn_s_barrier();
  }

  // ---- epilogue: dout = acc + (Cb+Db) ----
#pragma unroll
  for (int fj = 0; fj < 4; ++fj) {
    const int col = n0 + wn * 64 + fj * 16 + lr;
    const float cb = cbdb[col];
#pragma unroll
    for (int fi = 0; fi < 4; ++fi) {
      const int rowb = m0 + wm * 64 + fi * 16 + lk * 4;
#pragma unroll
      for (int j = 0; j < 4; ++j)
        dout[(size_t)(rowb + j) * DIM + col] = acc[fi][fj][j] + cb;
    }
  }
}

extern "C" void kernel_launch(void* const* d_in, const int* in_sizes, int n_in,
                              void* d_out, int out_size, void* d_ws, size_t ws_size,
                              hipStream_t stream) {
  const float* x  = (const float*)d_in[0];
  const float* A  = (const float*)d_in[1];
  const float* Bw = (const float*)d_in[2];
  const float* Bb = (const float*)d_in[3];
  const float* Cw = (const float*)d_in[4];
  const float* Cb = (const float*)d_in[5];
  const float* Dw = (const float*)d_in[6];
  const float* Db = (const float*)d_in[7];
  float* dout = (float*)d_out;

  char* ws = (char*)d_ws;
  unsigned short* xb   = (unsigned short*)(ws);              // 33,554,432 B
  unsigned short* bwb  = (unsigned short*)(ws + 33554432);   //    524,288 B
  unsigned short* wob  = (unsigned short*)(ws + 34078720);   //  2,621,440 B
  float*          G    = (float*)         (ws + 36700160);   // 16,777,216 B
  unsigned short* stb  = (unsigned short*)(ws + 53477376);   //  8,388,608 B
  float*          bb2  = (float*)         (ws + 61865984);   //      1,024 B
  float*          mP2  = (float*)         (ws + 61867008);   //      1,024 B
  float*          cbdb = (float*)         (ws + 61868032);   //      4,096 B -> 61,872,128

  // 1) dtype conversion + constants
  convert_kernel<<<16384 + 256 + 1024 + 1, 256, 0, stream>>>(
      x, A, Bw, Bb, Cw, Cb, Dw, Db, xb, bwb, wob, bb2, mP2, cbdb);
  // 2) G = (x @ Bw^T)*C2 + bb2
  gemm_G<<<256, 256, 0, stream>>>(xb, bwb, G, bb2);
  // 3) chunked recurrent scan -> states (bf16)
  scan_kernel<<<BATCH * 64, 256, 0, stream>>>(G, mP2, stb);
  // 4) dout = [states|x] @ [Cw|Dw]^T + (Cb+Db)
  gemm_out<<<512, 512, 0, stream>>>(stb, xb, wob, cbdb, dout);
}

// Round 6
// 100.643 us; speedup vs baseline: 1.0672x; 1.0672x over previous
//
#include <hip/hip_runtime.h>
#include <hip/hip_bf16.h>

#define DIM 1024
#define STATE 256
#define BATCH 4
#define SEQ 4096
#define M_TOT (BATCH * SEQ)  // 16384

typedef short short8 __attribute__((ext_vector_type(8)));
typedef float f32x4 __attribute__((ext_vector_type(4)));

__device__ __forceinline__ unsigned short f2bf(float f) {
  unsigned int u = __float_as_uint(f);
  u += 0x7fff + ((u >> 16) & 1);  // RNE
  return (unsigned short)(u >> 16);
}

__device__ __forceinline__ void gl_lds16(const void* g, void* l) {
  __builtin_amdgcn_global_load_lds(
      (const __attribute__((address_space(1))) void*)g,
      (__attribute__((address_space(3))) void*)l, 16, 0, 0);
}

#define C2F 2.8853900817779268f   // 2*log2(e)
#define LOG2EF 1.4426950408889634f
#define VMC(N) asm volatile("s_waitcnt vmcnt(" #N ")" ::: "memory")

// ---------------- convert_w: weights + constants only ------------------------
__global__ __launch_bounds__(256) void convert_w(
    const float* __restrict__ A, const float* __restrict__ Bw,
    const float* __restrict__ Bb, const float* __restrict__ Cw,
    const float* __restrict__ Cb, const float* __restrict__ Dw,
    const float* __restrict__ Db, unsigned short* __restrict__ bwb,
    unsigned short* __restrict__ wob, float* __restrict__ bb2,
    float* __restrict__ mP2, float* __restrict__ cbdb) {
  const int bx = blockIdx.x;
  const int t = threadIdx.x;
  if (bx < 256) {                      // bwb row per block
    int c = t * 4;
    const float4 v = *(const float4*)(Bw + (size_t)bx * DIM + c);
    *(ushort4*)(bwb + (size_t)bx * DIM + c) =
        make_ushort4(f2bf(v.x), f2bf(v.y), f2bf(v.z), f2bf(v.w));
  } else if (bx < 256 + 1024) {        // wob row e = [Cw[e,:] | Dw[e,:]]
    int e = bx - 256;
    if (t < 64) {
      const float4 v = *(const float4*)(Cw + (size_t)e * STATE + t * 4);
      *(ushort4*)(wob + (size_t)e * 1280 + t * 4) =
          make_ushort4(f2bf(v.x), f2bf(v.y), f2bf(v.z), f2bf(v.w));
    }
    const float4 v = *(const float4*)(Dw + (size_t)e * DIM + t * 4);
    *(ushort4*)(wob + (size_t)e * 1280 + 256 + t * 4) =
        make_ushort4(f2bf(v.x), f2bf(v.y), f2bf(v.z), f2bf(v.w));
  } else {                             // scan constants + out bias, one block
    const float P = C2F * __builtin_amdgcn_exp2f(A[t] * LOG2EF);
    bb2[t] = fmaf(Bb[t], C2F, P);
    mP2[t] = -2.0f * P;
#pragma unroll
    for (int k = 0; k < 4; ++k) {
      const int i = t * 4 + k;
      cbdb[i] = Cb[i] + Db[i];
    }
  }
}

// ---------------- gemm_GX: fused x-convert + G-projection + xb side-write ----
// G = (x @ Bw^T)*C2 + bb2 ; xb = bf16(x) (written by ntile==0 blocks).
// BM=BN=128, BK=64, 256 thr (4 waves 2x2), single-buffered LDS (A f32 32KB +
// B bf16 16KB), 8-chunk XOR swizzle (r4-proven 0-conflict). A fragments are
// converted f32->bf16 in-register after ds_read; xb is emitted from the same
// staged LDS tile (no extra HBM read of x).
__global__ __launch_bounds__(256, 3) void gemm_GX(
    const float* __restrict__ x,             // [16384][1024] f32
    const unsigned short* __restrict__ bwb,  // [256][1024] bf16
    float* __restrict__ G,                   // [16384][256] f32
    const float* __restrict__ bb2,
    unsigned short* __restrict__ xb)         // [16384][1024] bf16 (out)
{
  __shared__ char AsB[32768];  // A tile f32 [128][64], 16-chunk rows, XOR(r&7)
  __shared__ char BsB[16384];  // B tile bf16 [128][64], 8-chunk rows, XOR(r&7)

  const int tid = threadIdx.x;
  const int wave = tid >> 6;
  const int lane = tid & 63;
  const int lr = lane & 15;
  const int lk = lane >> 4;
  const int wr = wave >> 1;
  const int wc = wave & 1;

  // XCD swizzle: XCD k gets consecutive bs -> both n-tiles of an m-tile share L2
  const int bs = (blockIdx.x & 7) * 32 + (blockIdx.x >> 3);
  const int mtile = bs >> 1;
  const int ntile = bs & 1;
  const int m0 = mtile * 128;
  const int n0 = ntile * 128;

  f32x4 acc[4][4];
#pragma unroll
  for (int i = 0; i < 4; ++i)
#pragma unroll
    for (int j = 0; j < 4; ++j) acc[i][j] = (f32x4){0.f, 0.f, 0.f, 0.f};

  const char* xB  = (const char*)x;
  const char* bwB = (const char*)bwb;
  char* xbB = (char*)xb;

  for (int k0 = 0; k0 < 1024; k0 += 64) {
    // ---- stage A (f32, 32KB): 8 gload_lds/thread, source pre-swizzled ----
#pragma unroll
    for (int i = 0; i < 8; ++i) {
      const int s = i * 256 + tid;            // 2048 slots of 16B
      const int r = s >> 4;                   // row 0..127 (256B rows)
      const int c = (s & 15) ^ (r & 7);       // inverse-swizzled source chunk
      gl_lds16(xB + (size_t)(m0 + r) * 4096 + (size_t)k0 * 4 + c * 16,
               AsB + i * 4096 + wave * 1024);
    }
    // ---- stage B (bf16, 16KB): 4 gload_lds/thread ----
#pragma unroll
    for (int i = 0; i < 4; ++i) {
      const int s = i * 256 + tid;            // 1024 slots of 16B
      const int r = s >> 3;                   // row 0..127 (128B rows)
      const int c = (s & 7) ^ (r & 7);
      gl_lds16(bwB + (size_t)(n0 + r) * 2048 + (size_t)k0 * 2 + c * 16,
               BsB + i * 4096 + wave * 1024);
    }
    __syncthreads();  // drains vmcnt -> tiles complete

    // ---- MFMA over kk=0,1 with in-register f32->bf16 on A frags ----
#pragma unroll
    for (int kk = 0; kk < 2; ++kk) {
      short8 af[4], bfr[4];
#pragma unroll
      for (int f = 0; f < 4; ++f) {
        const int ra = wr * 64 + f * 16 + lr;
        const int swa = ra & 7;
        const f32x4 a0 = *(const f32x4*)(AsB + ra * 256 + (((kk * 8 + 2 * lk) ^ swa) << 4));
        const f32x4 a1 = *(const f32x4*)(AsB + ra * 256 + (((kk * 8 + 2 * lk + 1) ^ swa) << 4));
        short8 v;
#pragma unroll
        for (int j = 0; j < 4; ++j) {
          v[j]     = (short)f2bf(a0[j]);
          v[4 + j] = (short)f2bf(a1[j]);
        }
        af[f] = v;
        const int rb = wc * 64 + f * 16 + lr;
        bfr[f] = *(const short8*)(BsB + rb * 128 + (((kk * 4 + lk) ^ (rb & 7)) << 4));
      }
#pragma unroll
      for (int i = 0; i < 4; ++i)
#pragma unroll
        for (int j = 0; j < 4; ++j)
          acc[i][j] = __builtin_amdgcn_mfma_f32_16x16x32_bf16(af[i], bfr[j], acc[i][j], 0, 0, 0);
    }

    // ---- xb side-write from staged LDS tile (ntile==0 blocks only) ----
    if (ntile == 0) {
#pragma unroll
      for (int i = 0; i < 4; ++i) {
        const int o = i * 256 + tid;          // 1024 out-slots of 16B (8 bf16)
        const int r = o >> 3;                 // row 0..127
        const int oc = o & 7;                 // out-chunk (8 bf16 = 2 f32 chunks)
        const int sw = r & 7;
        const f32x4 a0 = *(const f32x4*)(AsB + r * 256 + (((2 * oc) ^ sw) << 4));
        const f32x4 a1 = *(const f32x4*)(AsB + r * 256 + (((2 * oc + 1) ^ sw) << 4));
        short8 v;
#pragma unroll
        for (int j = 0; j < 4; ++j) {
          v[j]     = (short)f2bf(a0[j]);
          v[4 + j] = (short)f2bf(a1[j]);
        }
        *(short8*)(xbB + (size_t)(m0 + r) * 2048 + (size_t)k0 * 2 + oc * 16) = v;
      }
    }
    __syncthreads();  // before next stage overwrites LDS
  }

  // ---- epilogue: G = acc*C2 + bb2 ----
#pragma unroll
  for (int fi = 0; fi < 4; ++fi)
#pragma unroll
    for (int fj = 0; fj < 4; ++fj)
#pragma unroll
      for (int j = 0; j < 4; ++j) {
        const int rg = m0 + wr * 64 + fi * 16 + lk * 4 + j;
        const int cg = n0 + wc * 64 + fj * 16 + lr;
        G[(size_t)rg * STATE + cg] = fmaf(acc[fi][fj][j], C2F, bb2[cg]);
      }
}

// ---------------- chunked-parallel scan with warmup ---------------------------
// W=128: contraction |exp(A)(1-s^2)| ~0.85-0.95/step -> warmup error <~1.4e-3.
__global__ __launch_bounds__(256) void scan_kernel(
    const float* __restrict__ G, const float* __restrict__ mP2arr,
    unsigned short* __restrict__ states) {
  const int b = blockIdx.x >> 6;
  const int chunk = blockIdx.x & 63;
  const int n = threadIdx.x;
  const int t0 = chunk * 64;
  const int start = (t0 > 128) ? (t0 - 128) : 0;
  const int nw = t0 - start;
  const int total = nw + 64;

  const float* g = G + ((size_t)b * SEQ + start) * STATE + n;
  unsigned short* q = states + ((size_t)b * SEQ + start) * STATE + n;
  const float mP2 = mP2arr[n];

  float r = 0.5f;
  constexpr int CH = 16;
  float cur[CH], nxt[CH];
#pragma unroll
  for (int j = 0; j < CH; ++j) cur[j] = g[(size_t)j * STATE];

  const int NC = total / CH;
  for (int c = 0; c < NC; ++c) {
    if (c + 1 < NC) {
      const float* pn = g + (size_t)(c + 1) * CH * STATE;
#pragma unroll
      for (int j = 0; j < CH; ++j) nxt[j] = pn[(size_t)j * STATE];
    }
    if (c * CH >= nw) {
      unsigned short* qc = q + (size_t)c * CH * STATE;
#pragma unroll
      for (int j = 0; j < CH; ++j) {
        const float t = fmaf(mP2, r, cur[j]);
        const float e = __builtin_amdgcn_exp2f(t);
        r = __builtin_amdgcn_rcpf(1.0f + e);
        const float s = fmaf(-2.0f, r, 1.0f);
        qc[(size_t)j * STATE] = f2bf(s);
      }
    } else {
#pragma unroll
      for (int j = 0; j < CH; ++j) {
        const float t = fmaf(mP2, r, cur[j]);
        const float e = __builtin_amdgcn_exp2f(t);
        r = __builtin_amdgcn_rcpf(1.0f + e);
      }
    }
    if (c + 1 < NC) {
#pragma unroll
      for (int j = 0; j < CH; ++j) cur[j] = nxt[j];
    }
  }
}

// ---------------- gemm_out: dout = [states|x] @ [Cw|Dw]^T + (Cb+Db) ----------
// Round-4 8-phase schedule (best measured: 50.4us) + lgkmcnt(8) partial drain
// in the 12-ds_read phases (m201 template item). BM=BN=256, BK=64, K=1280
// (20 tiles, 2/iter). 8 waves (2Mx4N). LDS 128KB: A 2x32KB + B 2x32KB dbuf.
#define PH(TILE, Q, STG, VMST)                                                 \
  do {                                                                         \
    const char* As = lds + ((TILE) & 1) * 32768;                               \
    const char* Bs = lds + 65536 + ((TILE) & 1) * 32768;                       \
    if ((Q) == 0) {                                                            \
      _Pragma("unroll") for (int fj = 0; fj < 4; ++fj) {                       \
        const int r = wn * 64 + fj * 16 + lr;                                  \
        _Pragma("unroll") for (int kk = 0; kk < 2; ++kk)                       \
          bfr[fj][kk] = *(const short8*)(Bs + r * 128 +                        \
                                         (((kk * 4 + lk) ^ (r & 7)) << 4));    \
      }                                                                        \
    }                                                                          \
    short8 af[2][2];                                                           \
    _Pragma("unroll") for (int fl = 0; fl < 2; ++fl) {                         \
      const int r = wm * 128 + (Q) * 32 + fl * 16 + lr;                        \
      _Pragma("unroll") for (int kk = 0; kk < 2; ++kk)                         \
        af[fl][kk] = *(const short8*)(As + r * 128 +                           \
                                      (((kk * 4 + lk) ^ (r & 7)) << 4));       \
    }                                                                          \
    STG;                                                                       \
    if ((Q) == 0) asm volatile("s_waitcnt lgkmcnt(8)" ::: "memory");           \
    __builtin_amdgcn_s_barrier();                                              \
    __builtin_amdgcn_s_setprio(1);                                             \
    _Pragma("unroll") for (int kk = 0; kk < 2; ++kk)                           \
      _Pragma("unroll") for (int fl = 0; fl < 2; ++fl)                         \
        _Pragma("unroll") for (int fj = 0; fj < 4; ++fj)                       \
          acc[(Q) * 2 + fl][fj] = __builtin_amdgcn_mfma_f32_16x16x32_bf16(     \
              af[fl][kk], bfr[fj][kk], acc[(Q) * 2 + fl][fj], 0, 0, 0);        \
    __builtin_amdgcn_s_setprio(0);                                             \
    VMST;                                                                      \
    __builtin_amdgcn_s_barrier();                                              \
  } while (0)

__global__ __launch_bounds__(512, 2) void gemm_out(
    const unsigned short* __restrict__ stb,  // [16384][256] bf16
    const unsigned short* __restrict__ xb,   // [16384][1024] bf16
    const unsigned short* __restrict__ wob,  // [1024][1280] bf16
    const float* __restrict__ cbdb,          // [1024]
    float* __restrict__ dout)                // [16384][1024] f32
{
  __shared__ char lds[131072];  // A: 2x32KB @0, B: 2x32KB @65536

  const int tid = threadIdx.x;
  const int wave = tid >> 6;
  const int lane = tid & 63;
  const int lr = lane & 15;
  const int lk = lane >> 4;
  const int wm = wave >> 2;  // 0..1
  const int wn = wave & 3;   // 0..3

  const int bs = ((blockIdx.x & 7) << 5) | (blockIdx.x >> 3);  // XCD swizzle (256%8==0)
  const int m0 = (bs >> 2) * 256;
  const int n0 = (bs & 3) * 256;

  const char* stbB = (const char*)stb;
  const char* xbB  = (const char*)xb;
  const char* wobB = (const char*)wob;

  f32x4 acc[8][4];
#pragma unroll
  for (int i = 0; i < 8; ++i)
#pragma unroll
    for (int j = 0; j < 4; ++j) acc[i][j] = (f32x4){0.f, 0.f, 0.f, 0.f};

  // stage one half-tile (128 rows x 64 cols bf16 = 16KB = 2 gload_lds/thread)
  auto stageA = [&](int kt, int h) {
    if (kt >= 20) return;
    const char* base;
    size_t str;
    size_t colb;
    if (kt < 4) { base = stbB; str = 512;  colb = (size_t)kt * 128; }
    else        { base = xbB;  str = 2048; colb = (size_t)(kt - 4) * 128; }
    base += (size_t)m0 * str;
#pragma unroll
    for (int i2 = 0; i2 < 2; ++i2) {
      const int s = i2 * 512 + tid;
      const int r = s >> 3;                    // 0..127 within half
      const int cl = (s & 7) ^ (r & 7);        // inverse-swizzled source chunk
      gl_lds16(base + (size_t)(h * 128 + r) * str + colb + cl * 16,
               lds + ((kt & 1) * 32768) + h * 16384 + i2 * 8192 + wave * 1024);
    }
  };
  auto stageB = [&](int kt, int h) {
    if (kt >= 20) return;
#pragma unroll
    for (int i2 = 0; i2 < 2; ++i2) {
      const int s = i2 * 512 + tid;
      const int r = s >> 3;
      const int cl = (s & 7) ^ (r & 7);
      gl_lds16(wobB + (size_t)(n0 + h * 128 + r) * 2560 + (size_t)kt * 128 + cl * 16,
               lds + 65536 + ((kt & 1) * 32768) + h * 16384 + i2 * 8192 + wave * 1024);
    }
  };

  // ---- prologue: A(0), B(0), B(1) = 6 half-tiles (12 loads/wave) ----
  stageA(0, 0); stageA(0, 1);
  stageB(0, 0); stageB(0, 1);
  stageB(1, 0); stageB(1, 1);
  VMC(4);  // A(0),B(0) complete; B(1)'s 4 loads may fly
  __builtin_amdgcn_s_barrier();

  short8 bfr[4][2];
  for (int i = 0; i < 10; ++i) {
    const int e = 2 * i, o = e + 1;
    PH(e, 0, stageA(o, 0), );
    PH(e, 1, stageA(o, 1), );
    PH(e, 2, stageB(e + 2, 0), );
    PH(e, 3, stageB(e + 2, 1), if (i == 9) { VMC(0); } else { VMC(4); });
    PH(o, 0, stageA(e + 2, 0), );
    PH(o, 1, stageA(e + 2, 1), );
    PH(o, 2, stageB(o + 2, 0), );
    PH(o, 3, stageB(o + 2, 1), VMC(4));
  }

  // ---- epilogue: dout = acc + (Cb+Db) ----
#pragma unroll
  for (int fj = 0; fj < 4; ++fj) {
    const int col = n0 + wn * 64 + fj * 16 + lr;
    const float cb = cbdb[col];
#pragma unroll
    for (int m = 0; m < 8; ++m) {
      const int rowb = m0 + wm * 128 + m * 16 + lk * 4;
#pragma unroll
      for (int j = 0; j < 4; ++j)
        dout[(size_t)(rowb + j) * DIM + col] = acc[m][fj][j] + cb;
    }
  }
}

extern "C" void kernel_launch(void* const* d_in, const int* in_sizes, int n_in,
                              void* d_out, int out_size, void* d_ws, size_t ws_size,
                              hipStream_t stream) {
  const float* x  = (const float*)d_in[0];
  const float* A  = (const float*)d_in[1];
  const float* Bw = (const float*)d_in[2];
  const float* Bb = (const float*)d_in[3];
  const float* Cw = (const float*)d_in[4];
  const float* Cb = (const float*)d_in[5];
  const float* Dw = (const float*)d_in[6];
  const float* Db = (const float*)d_in[7];
  float* dout = (float*)d_out;

  char* ws = (char*)d_ws;
  unsigned short* xb   = (unsigned short*)(ws);              // 33,554,432 B
  unsigned short* bwb  = (unsigned short*)(ws + 33554432);   //    524,288 B
  unsigned short* wob  = (unsigned short*)(ws + 34078720);   //  2,621,440 B
  float*          G    = (float*)         (ws + 36700160);   // 16,777,216 B
  unsigned short* stb  = (unsigned short*)(ws + 53477376);   //  8,388,608 B
  float*          bb2  = (float*)         (ws + 61865984);   //      1,024 B
  float*          mP2  = (float*)         (ws + 61867008);   //      1,024 B
  float*          cbdb = (float*)         (ws + 61868032);   //      4,096 B -> 61,872,128

  // 1) weight conversion + constants (tiny)
  convert_w<<<256 + 1024 + 1, 256, 0, stream>>>(
      A, Bw, Bb, Cw, Cb, Dw, Db, bwb, wob, bb2, mP2, cbdb);
  // 2) fused: G = (x @ Bw^T)*C2 + bb2 ; xb = bf16(x)
  gemm_GX<<<256, 256, 0, stream>>>(x, bwb, G, bb2, xb);
  // 3) chunked recurrent scan -> states (bf16)
  scan_kernel<<<BATCH * 64, 256, 0, stream>>>(G, mP2, stb);
  // 4) dout = [states|x] @ [Cw|Dw]^T + (Cb+Db)
  gemm_out<<<256, 512, 0, stream>>>(stb, xb, wob, cbdb, dout);
}

// Round 7
// 96.102 us; speedup vs baseline: 1.1176x; 1.0472x over previous
//
#include <hip/hip_runtime.h>
#include <hip/hip_bf16.h>

#define DIM 1024
#define STATE 256
#define BATCH 4
#define SEQ 4096
#define M_TOT (BATCH * SEQ)  // 16384

typedef short short8 __attribute__((ext_vector_type(8)));
typedef float f32x4 __attribute__((ext_vector_type(4)));

__device__ __forceinline__ unsigned short f2bf(float f) {
  unsigned int u = __float_as_uint(f);
  u += 0x7fff + ((u >> 16) & 1);  // RNE
  return (unsigned short)(u >> 16);
}

__device__ __forceinline__ void gl_lds16(const void* g, void* l) {
  __builtin_amdgcn_global_load_lds(
      (const __attribute__((address_space(1))) void*)g,
      (__attribute__((address_space(3))) void*)l, 16, 0, 0);
}

#define C2F 2.8853900817779268f   // 2*log2(e)
#define LOG2EF 1.4426950408889634f
#define VMC(N) asm volatile("s_waitcnt vmcnt(" #N ")" ::: "memory")

// ---------------- convert_w: weights + constants only ------------------------
__global__ __launch_bounds__(256) void convert_w(
    const float* __restrict__ A, const float* __restrict__ Bw,
    const float* __restrict__ Bb, const float* __restrict__ Cw,
    const float* __restrict__ Cb, const float* __restrict__ Dw,
    const float* __restrict__ Db, unsigned short* __restrict__ bwb,
    unsigned short* __restrict__ wob, float* __restrict__ bb2,
    float* __restrict__ mP2, float* __restrict__ cbdb) {
  const int bx = blockIdx.x;
  const int t = threadIdx.x;
  if (bx < 256) {                      // bwb row per block
    int c = t * 4;
    const float4 v = *(const float4*)(Bw + (size_t)bx * DIM + c);
    *(ushort4*)(bwb + (size_t)bx * DIM + c) =
        make_ushort4(f2bf(v.x), f2bf(v.y), f2bf(v.z), f2bf(v.w));
  } else if (bx < 256 + 1024) {        // wob row e = [Cw[e,:] | Dw[e,:]]
    int e = bx - 256;
    if (t < 64) {
      const float4 v = *(const float4*)(Cw + (size_t)e * STATE + t * 4);
      *(ushort4*)(wob + (size_t)e * 1280 + t * 4) =
          make_ushort4(f2bf(v.x), f2bf(v.y), f2bf(v.z), f2bf(v.w));
    }
    const float4 v = *(const float4*)(Dw + (size_t)e * DIM + t * 4);
    *(ushort4*)(wob + (size_t)e * 1280 + 256 + t * 4) =
        make_ushort4(f2bf(v.x), f2bf(v.y), f2bf(v.z), f2bf(v.w));
  } else {                             // scan constants + out bias, one block
    const float P = C2F * __builtin_amdgcn_exp2f(A[t] * LOG2EF);
    bb2[t] = fmaf(Bb[t], C2F, P);
    mP2[t] = -2.0f * P;
#pragma unroll
    for (int k = 0; k < 4; ++k) {
      const int i = t * 4 + k;
      cbdb[i] = Cb[i] + Db[i];
    }
  }
}

// ---------------- gemm_GX: fused x-convert + G-projection + xb side-write ----
// G = (x @ Bw^T)*C2 + bb2 ; xb = bf16(x) (stored from converted A register
// fragments, wave 0). BM=32, BN=256 (full STATE -> x read ONCE; bwb from L2),
// BK=32, grid 512 = 2 blocks/CU. 3-slot LDS ring (3x20KB), one barrier/iter,
// counted vmcnt: each wave waits its OWN tile-(t+1) loads pre-barrier ->
// post-barrier the slot is globally complete (r3-proven skeleton).
// 4 waves (1m x 4n), per-wave 32x64 out, acc[2][4].
__global__ __launch_bounds__(256, 2) void gemm_GX(
    const float* __restrict__ x,             // [16384][1024] f32
    const unsigned short* __restrict__ bwb,  // [256][1024] bf16
    float* __restrict__ G,                   // [16384][256] f32
    const float* __restrict__ bb2,
    unsigned short* __restrict__ xb)         // [16384][1024] bf16 (out)
{
  __shared__ char lds[61440];  // 3 slots x 20480 (A f32 4KB @0, B bf16 16KB @4096)

  const int tid = threadIdx.x;
  const int wave = tid >> 6;   // wn 0..3 (col group)
  const int lane = tid & 63;
  const int lr = lane & 15;
  const int lk = lane >> 4;
  const int m0 = blockIdx.x * 32;

  f32x4 acc[2][4];
#pragma unroll
  for (int i = 0; i < 2; ++i)
#pragma unroll
    for (int j = 0; j < 4; ++j) acc[i][j] = (f32x4){0.f, 0.f, 0.f, 0.f};

  const char* xB  = (const char*)x;
  const char* bwB = (const char*)bwb;
  char* xbB = (char*)xb;

  // stage K-tile kt into slot kt%3: A 4KB f32 (1 load/thr, chunk-XOR(r&7)),
  // B 16KB bf16 (4 loads/thr, linear). 5 loads/thread total.
  auto stage = [&](int kt) {
    if (kt >= 32) return;
    char* slot = lds + (kt % 3) * 20480;
    {
      const int r = tid >> 3;                 // row 0..31
      const int c = (tid & 7) ^ (r & 7);      // inverse-swizzled source chunk
      gl_lds16(xB + (size_t)(m0 + r) * 4096 + (size_t)kt * 128 + c * 16,
               slot + wave * 1024);
    }
#pragma unroll
    for (int i = 0; i < 4; ++i) {
      const int s = i * 256 + tid;
      const int r = s >> 2;                   // bwb row (= col) 0..255
      const int c = s & 3;
      gl_lds16(bwB + (size_t)r * 2048 + (size_t)kt * 64 + c * 16,
               slot + 4096 + i * 4096 + wave * 1024);
    }
  };

  // prologue
  stage(0); stage(1);
  VMC(5);  // own stage(0) loads complete; stage(1) may fly
  __builtin_amdgcn_s_barrier();

  for (int t = 0; t < 32; ++t) {
    stage(t + 2);  // slot (t+2)%3 == (t-1)%3: its readers finished last iter

    const char* As = lds + (t % 3) * 20480;
    const char* Bs = As + 4096;

    short8 af[2], bfr[4];
#pragma unroll
    for (int f = 0; f < 2; ++f) {
      const int row = f * 16 + lr;
      const int sw = row & 7;
      const f32x4 a0 = *(const f32x4*)(As + row * 128 + (((2 * lk)     ^ sw) << 4));
      const f32x4 a1 = *(const f32x4*)(As + row * 128 + (((2 * lk + 1) ^ sw) << 4));
      short8 v;
#pragma unroll
      for (int j = 0; j < 4; ++j) {
        v[j]     = (short)f2bf(a0[j]);
        v[4 + j] = (short)f2bf(a1[j]);
      }
      af[f] = v;
    }
#pragma unroll
    for (int fj = 0; fj < 4; ++fj) {
      const int rb = wave * 64 + fj * 16 + lr;
      bfr[fj] = *(const short8*)(Bs + rb * 64 + (lk << 4));
    }
#pragma unroll
    for (int f = 0; f < 2; ++f)
#pragma unroll
      for (int fj = 0; fj < 4; ++fj)
        acc[f][fj] = __builtin_amdgcn_mfma_f32_16x16x32_bf16(af[f], bfr[fj], acc[f][fj], 0, 0, 0);

    if (wave == 0) {  // xb side-write from converted register fragments
#pragma unroll
      for (int f = 0; f < 2; ++f) {
        const int row = f * 16 + lr;
        *(short8*)(xbB + (size_t)(m0 + row) * 2048 + (size_t)t * 64 + lk * 16) = af[f];
      }
      if (t < 30) { VMC(7); } else { VMC(0); }  // 7 = stage(t+2)5 + stores(t)2
    } else {
      if (t < 30) { VMC(5); } else { VMC(0); }  // 5 = stage(t+2)
    }
    __builtin_amdgcn_s_barrier();
  }

  // epilogue: G = acc*C2 + bb2
#pragma unroll
  for (int f = 0; f < 2; ++f)
#pragma unroll
    for (int fj = 0; fj < 4; ++fj)
#pragma unroll
      for (int j = 0; j < 4; ++j) {
        const int rg = m0 + f * 16 + lk * 4 + j;
        const int cg = wave * 64 + fj * 16 + lr;
        G[(size_t)rg * STATE + cg] = fmaf(acc[f][fj][j], C2F, bb2[cg]);
      }
}

// ---------------- chunked-parallel scan with warmup ---------------------------
// W=128: contraction |exp(A)(1-s^2)| ~0.85-0.95/step -> warmup error <~1.4e-3.
__global__ __launch_bounds__(256) void scan_kernel(
    const float* __restrict__ G, const float* __restrict__ mP2arr,
    unsigned short* __restrict__ states) {
  const int b = blockIdx.x >> 6;
  const int chunk = blockIdx.x & 63;
  const int n = threadIdx.x;
  const int t0 = chunk * 64;
  const int start = (t0 > 128) ? (t0 - 128) : 0;
  const int nw = t0 - start;
  const int total = nw + 64;

  const float* g = G + ((size_t)b * SEQ + start) * STATE + n;
  unsigned short* q = states + ((size_t)b * SEQ + start) * STATE + n;
  const float mP2 = mP2arr[n];

  float r = 0.5f;
  constexpr int CH = 16;
  float cur[CH], nxt[CH];
#pragma unroll
  for (int j = 0; j < CH; ++j) cur[j] = g[(size_t)j * STATE];

  const int NC = total / CH;
  for (int c = 0; c < NC; ++c) {
    if (c + 1 < NC) {
      const float* pn = g + (size_t)(c + 1) * CH * STATE;
#pragma unroll
      for (int j = 0; j < CH; ++j) nxt[j] = pn[(size_t)j * STATE];
    }
    if (c * CH >= nw) {
      unsigned short* qc = q + (size_t)c * CH * STATE;
#pragma unroll
      for (int j = 0; j < CH; ++j) {
        const float t = fmaf(mP2, r, cur[j]);
        const float e = __builtin_amdgcn_exp2f(t);
        r = __builtin_amdgcn_rcpf(1.0f + e);
        const float s = fmaf(-2.0f, r, 1.0f);
        qc[(size_t)j * STATE] = f2bf(s);
      }
    } else {
#pragma unroll
      for (int j = 0; j < CH; ++j) {
        const float t = fmaf(mP2, r, cur[j]);
        const float e = __builtin_amdgcn_exp2f(t);
        r = __builtin_amdgcn_rcpf(1.0f + e);
      }
    }
    if (c + 1 < NC) {
#pragma unroll
      for (int j = 0; j < CH; ++j) cur[j] = nxt[j];
    }
  }
}

// ---------------- gemm_out: dout = [states|x] @ [Cw|Dw]^T + (Cb+Db) ----------
// Round-4/6 8-phase schedule (best measured 49.4us). BM=BN=256, BK=64, K=1280
// (20 tiles, 2/iter). 8 waves (2Mx4N). LDS 128KB: A 2x32KB + B 2x32KB dbuf.
#define PH(TILE, Q, STG, VMST)                                                 \
  do {                                                                         \
    const char* As = lds + ((TILE) & 1) * 32768;                               \
    const char* Bs = lds + 65536 + ((TILE) & 1) * 32768;                       \
    if ((Q) == 0) {                                                            \
      _Pragma("unroll") for (int fj = 0; fj < 4; ++fj) {                       \
        const int r = wn * 64 + fj * 16 + lr;                                  \
        _Pragma("unroll") for (int kk = 0; kk < 2; ++kk)                       \
          bfr[fj][kk] = *(const short8*)(Bs + r * 128 +                        \
                                         (((kk * 4 + lk) ^ (r & 7)) << 4));    \
      }                                                                        \
    }                                                                          \
    short8 af[2][2];                                                           \
    _Pragma("unroll") for (int fl = 0; fl < 2; ++fl) {                         \
      const int r = wm * 128 + (Q) * 32 + fl * 16 + lr;                        \
      _Pragma("unroll") for (int kk = 0; kk < 2; ++kk)                         \
        af[fl][kk] = *(const short8*)(As + r * 128 +                           \
                                      (((kk * 4 + lk) ^ (r & 7)) << 4));       \
    }                                                                          \
    STG;                                                                       \
    if ((Q) == 0) asm volatile("s_waitcnt lgkmcnt(8)" ::: "memory");           \
    __builtin_amdgcn_s_barrier();                                              \
    __builtin_amdgcn_s_setprio(1);                                             \
    _Pragma("unroll") for (int kk = 0; kk < 2; ++kk)                           \
      _Pragma("unroll") for (int fl = 0; fl < 2; ++fl)                         \
        _Pragma("unroll") for (int fj = 0; fj < 4; ++fj)                       \
          acc[(Q) * 2 + fl][fj] = __builtin_amdgcn_mfma_f32_16x16x32_bf16(     \
              af[fl][kk], bfr[fj][kk], acc[(Q) * 2 + fl][fj], 0, 0, 0);        \
    __builtin_amdgcn_s_setprio(0);                                             \
    VMST;                                                                      \
    __builtin_amdgcn_s_barrier();                                              \
  } while (0)

__global__ __launch_bounds__(512, 2) void gemm_out(
    const unsigned short* __restrict__ stb,  // [16384][256] bf16
    const unsigned short* __restrict__ xb,   // [16384][1024] bf16
    const unsigned short* __restrict__ wob,  // [1024][1280] bf16
    const float* __restrict__ cbdb,          // [1024]
    float* __restrict__ dout)                // [16384][1024] f32
{
  __shared__ char lds[131072];  // A: 2x32KB @0, B: 2x32KB @65536

  const int tid = threadIdx.x;
  const int wave = tid >> 6;
  const int lane = tid & 63;
  const int lr = lane & 15;
  const int lk = lane >> 4;
  const int wm = wave >> 2;  // 0..1
  const int wn = wave & 3;   // 0..3

  const int bs = ((blockIdx.x & 7) << 5) | (blockIdx.x >> 3);  // XCD swizzle (256%8==0)
  const int m0 = (bs >> 2) * 256;
  const int n0 = (bs & 3) * 256;

  const char* stbB = (const char*)stb;
  const char* xbB  = (const char*)xb;
  const char* wobB = (const char*)wob;

  f32x4 acc[8][4];
#pragma unroll
  for (int i = 0; i < 8; ++i)
#pragma unroll
    for (int j = 0; j < 4; ++j) acc[i][j] = (f32x4){0.f, 0.f, 0.f, 0.f};

  // stage one half-tile (128 rows x 64 cols bf16 = 16KB = 2 gload_lds/thread)
  auto stageA = [&](int kt, int h) {
    if (kt >= 20) return;
    const char* base;
    size_t str;
    size_t colb;
    if (kt < 4) { base = stbB; str = 512;  colb = (size_t)kt * 128; }
    else        { base = xbB;  str = 2048; colb = (size_t)(kt - 4) * 128; }
    base += (size_t)m0 * str;
#pragma unroll
    for (int i2 = 0; i2 < 2; ++i2) {
      const int s = i2 * 512 + tid;
      const int r = s >> 3;                    // 0..127 within half
      const int cl = (s & 7) ^ (r & 7);        // inverse-swizzled source chunk
      gl_lds16(base + (size_t)(h * 128 + r) * str + colb + cl * 16,
               lds + ((kt & 1) * 32768) + h * 16384 + i2 * 8192 + wave * 1024);
    }
  };
  auto stageB = [&](int kt, int h) {
    if (kt >= 20) return;
#pragma unroll
    for (int i2 = 0; i2 < 2; ++i2) {
      const int s = i2 * 512 + tid;
      const int r = s >> 3;
      const int cl = (s & 7) ^ (r & 7);
      gl_lds16(wobB + (size_t)(n0 + h * 128 + r) * 2560 + (size_t)kt * 128 + cl * 16,
               lds + 65536 + ((kt & 1) * 32768) + h * 16384 + i2 * 8192 + wave * 1024);
    }
  };

  // ---- prologue: A(0), B(0), B(1) = 6 half-tiles (12 loads/wave) ----
  stageA(0, 0); stageA(0, 1);
  stageB(0, 0); stageB(0, 1);
  stageB(1, 0); stageB(1, 1);
  VMC(4);  // A(0),B(0) complete; B(1)'s 4 loads may fly
  __builtin_amdgcn_s_barrier();

  short8 bfr[4][2];
  for (int i = 0; i < 10; ++i) {
    const int e = 2 * i, o = e + 1;
    PH(e, 0, stageA(o, 0), );
    PH(e, 1, stageA(o, 1), );
    PH(e, 2, stageB(e + 2, 0), );
    PH(e, 3, stageB(e + 2, 1), if (i == 9) { VMC(0); } else { VMC(4); });
    PH(o, 0, stageA(e + 2, 0), );
    PH(o, 1, stageA(e + 2, 1), );
    PH(o, 2, stageB(o + 2, 0), );
    PH(o, 3, stageB(o + 2, 1), VMC(4));
  }

  // ---- epilogue: dout = acc + (Cb+Db) ----
#pragma unroll
  for (int fj = 0; fj < 4; ++fj) {
    const int col = n0 + wn * 64 + fj * 16 + lr;
    const float cb = cbdb[col];
#pragma unroll
    for (int m = 0; m < 8; ++m) {
      const int rowb = m0 + wm * 128 + m * 16 + lk * 4;
#pragma unroll
      for (int j = 0; j < 4; ++j)
        dout[(size_t)(rowb + j) * DIM + col] = acc[m][fj][j] + cb;
    }
  }
}

extern "C" void kernel_launch(void* const* d_in, const int* in_sizes, int n_in,
                              void* d_out, int out_size, void* d_ws, size_t ws_size,
                              hipStream_t stream) {
  const float* x  = (const float*)d_in[0];
  const float* A  = (const float*)d_in[1];
  const float* Bw = (const float*)d_in[2];
  const float* Bb = (const float*)d_in[3];
  const float* Cw = (const float*)d_in[4];
  const float* Cb = (const float*)d_in[5];
  const float* Dw = (const float*)d_in[6];
  const float* Db = (const float*)d_in[7];
  float* dout = (float*)d_out;

  char* ws = (char*)d_ws;
  unsigned short* xb   = (unsigned short*)(ws);              // 33,554,432 B
  unsigned short* bwb  = (unsigned short*)(ws + 33554432);   //    524,288 B
  unsigned short* wob  = (unsigned short*)(ws + 34078720);   //  2,621,440 B
  float*          G    = (float*)         (ws + 36700160);   // 16,777,216 B
  unsigned short* stb  = (unsigned short*)(ws + 53477376);   //  8,388,608 B
  float*          bb2  = (float*)         (ws + 61865984);   //      1,024 B
  float*          mP2  = (float*)         (ws + 61867008);   //      1,024 B
  float*          cbdb = (float*)         (ws + 61868032);   //      4,096 B -> 61,872,128

  // 1) weight conversion + constants (tiny)
  convert_w<<<256 + 1024 + 1, 256, 0, stream>>>(
      A, Bw, Bb, Cw, Cb, Dw, Db, bwb, wob, bb2, mP2, cbdb);
  // 2) fused: G = (x @ Bw^T)*C2 + bb2 ; xb = bf16(x)  [BW-rider, 2 blocks/CU]
  gemm_GX<<<512, 256, 0, stream>>>(x, bwb, G, bb2, xb);
  // 3) chunked recurrent scan -> states (bf16)
  scan_kernel<<<BATCH * 64, 256, 0, stream>>>(G, mP2, stb);
  // 4) dout = [states|x] @ [Cw|Dw]^T + (Cb+Db)
  gemm_out<<<256, 512, 0, stream>>>(stb, xb, wob, cbdb, dout);
}

// Round 8
// 96.099 us; speedup vs baseline: 1.1177x; 1.0000x over previous
//
#include <hip/hip_runtime.h>
#include <hip/hip_bf16.h>

#define DIM 1024
#define STATE 256
#define BATCH 4
#define SEQ 4096
#define M_TOT (BATCH * SEQ)  // 16384

typedef short short8 __attribute__((ext_vector_type(8)));
typedef float f32x4 __attribute__((ext_vector_type(4)));

__device__ __forceinline__ unsigned short f2bf(float f) {
  unsigned int u = __float_as_uint(f);
  u += 0x7fff + ((u >> 16) & 1);  // RNE
  return (unsigned short)(u >> 16);
}

__device__ __forceinline__ void gl_lds16(const void* g, void* l) {
  __builtin_amdgcn_global_load_lds(
      (const __attribute__((address_space(1))) void*)g,
      (__attribute__((address_space(3))) void*)l, 16, 0, 0);
}

#define C2F 2.8853900817779268f   // 2*log2(e)
#define LOG2EF 1.4426950408889634f
#define VMC(N) asm volatile("s_waitcnt vmcnt(" #N ")" ::: "memory")

// ---------------- convert_w: weights + constants only ------------------------
__global__ __launch_bounds__(256) void convert_w(
    const float* __restrict__ A, const float* __restrict__ Bw,
    const float* __restrict__ Bb, const float* __restrict__ Cw,
    const float* __restrict__ Cb, const float* __restrict__ Dw,
    const float* __restrict__ Db, unsigned short* __restrict__ bwb,
    unsigned short* __restrict__ wob, float* __restrict__ bb2,
    float* __restrict__ mP2, float* __restrict__ cbdb) {
  const int bx = blockIdx.x;
  const int t = threadIdx.x;
  if (bx < 256) {                      // bwb row per block
    int c = t * 4;
    const float4 v = *(const float4*)(Bw + (size_t)bx * DIM + c);
    *(ushort4*)(bwb + (size_t)bx * DIM + c) =
        make_ushort4(f2bf(v.x), f2bf(v.y), f2bf(v.z), f2bf(v.w));
  } else if (bx < 256 + 1024) {        // wob row e = [Cw[e,:] | Dw[e,:]]
    int e = bx - 256;
    if (t < 64) {
      const float4 v = *(const float4*)(Cw + (size_t)e * STATE + t * 4);
      *(ushort4*)(wob + (size_t)e * 1280 + t * 4) =
          make_ushort4(f2bf(v.x), f2bf(v.y), f2bf(v.z), f2bf(v.w));
    }
    const float4 v = *(const float4*)(Dw + (size_t)e * DIM + t * 4);
    *(ushort4*)(wob + (size_t)e * 1280 + 256 + t * 4) =
        make_ushort4(f2bf(v.x), f2bf(v.y), f2bf(v.z), f2bf(v.w));
  } else {                             // scan constants + out bias, one block
    const float P = C2F * __builtin_amdgcn_exp2f(A[t] * LOG2EF);
    bb2[t] = fmaf(Bb[t], C2F, P);
    mP2[t] = -2.0f * P;
#pragma unroll
    for (int k = 0; k < 4; ++k) {
      const int i = t * 4 + k;
      cbdb[i] = Cb[i] + Db[i];
    }
  }
}

// ---------------- gemm_GX v3: fused x-convert + G-projection + xb write ------
// G = (x @ Bw^T)*C2 + bb2 ; xb = bf16(x). BM=32, BN=256, BK=32, grid 512 =
// 2 blocks/CU. 4-slot LDS ring (4x20KB = 80KB; 2 blocks = 160KB exactly),
// prefetch distance 3. Counted vmcnt is STORE-SOUND: N = loads newer than the
// target stage group (10 = st(t+2)+st(t+3)); even if xb stores retire first,
// >=5 load completions are forced => st(t+1) drained. Stores spread: wave w
// stores xb for tiles t%4==w (every wave holds the full A fragment).
// B LDS layout: row-pairs (p = n>>1) of 128B, chunk XOR (p&7): every bank
// gets exactly 8 accesses per wave read (floor). A: 128B f32 rows, XOR (r&7).
__global__ __launch_bounds__(256, 2) void gemm_GX(
    const float* __restrict__ x,             // [16384][1024] f32
    const unsigned short* __restrict__ bwb,  // [256][1024] bf16
    float* __restrict__ G,                   // [16384][256] f32
    const float* __restrict__ bb2,
    unsigned short* __restrict__ xb)         // [16384][1024] bf16 (out)
{
  __shared__ char lds[81920];  // 4 slots x 20480 (A f32 4KB @0, B bf16 16KB @4096)

  const int tid = threadIdx.x;
  const int wave = tid >> 6;   // n-column group 0..3
  const int lane = tid & 63;
  const int lr = lane & 15;
  const int lk = lane >> 4;
  const int m0 = blockIdx.x * 32;

  f32x4 acc[2][4];
#pragma unroll
  for (int i = 0; i < 2; ++i)
#pragma unroll
    for (int j = 0; j < 4; ++j) acc[i][j] = (f32x4){0.f, 0.f, 0.f, 0.f};

  const char* xB  = (const char*)x;
  const char* bwB = (const char*)bwb;
  char* xbB = (char*)xb;

  // stage K-tile kt into slot kt&3: A 1 load/thr, B 4 loads/thr (5 total).
  auto stage = [&](int kt) {
    if (kt >= 32) return;
    char* slot = lds + (kt & 3) * 20480;
    {  // A: [32 rows][128B f32], chunk XOR (r&7); source pre-swizzled
      const int r = tid >> 3;                 // row 0..31
      const int c = (tid & 7) ^ (r & 7);
      gl_lds16(xB + (size_t)(m0 + r) * 4096 + (size_t)kt * 128 + c * 16,
               slot + wave * 1024);
    }
#pragma unroll
    for (int i = 0; i < 4; ++i) {  // B: row-pair layout [p=n>>1][128B], XOR(p&7)
      const int s = i * 256 + tid;            // slot index 0..1023 (16B units)
      const int p = s >> 3;                   // row-pair 0..127
      const int cp = s & 7;
      const int c = cp ^ (p & 7);             // logical chunk
      const int n = 2 * p + (c >> 2);         // bwb row
      const int kc = c & 3;                   // 16B chunk within 64B k-window
      gl_lds16(bwB + (size_t)n * 2048 + (size_t)kt * 64 + kc * 16,
               slot + 4096 + i * 4096 + wave * 1024);
    }
  };

  // prologue: tiles 0,1,2 in flight (15 loads/thread)
  stage(0); stage(1); stage(2);
  VMC(10);  // newer-than-st(0) loads = 10 -> st(0) drained
  __builtin_amdgcn_s_barrier();

  for (int t = 0; t < 32; ++t) {
    stage(t + 3);  // slot (t+3)&3 == (t-1)&3: readers finished last iter

    const char* As = lds + (t & 3) * 20480;
    const char* Bs = As + 4096;

    short8 af[2], bfr[4];
#pragma unroll
    for (int f = 0; f < 2; ++f) {
      const int row = f * 16 + lr;
      const int sw = row & 7;
      const f32x4 a0 = *(const f32x4*)(As + row * 128 + (((2 * lk)     ^ sw) << 4));
      const f32x4 a1 = *(const f32x4*)(As + row * 128 + (((2 * lk + 1) ^ sw) << 4));
      short8 v;
#pragma unroll
      for (int j = 0; j < 4; ++j) {
        v[j]     = (short)f2bf(a0[j]);
        v[4 + j] = (short)f2bf(a1[j]);
      }
      af[f] = v;
    }
#pragma unroll
    for (int fj = 0; fj < 4; ++fj) {
      const int n = wave * 64 + fj * 16 + lr;
      const int p = n >> 1;
      const int cp = (((n & 1) * 4 + lk)) ^ (p & 7);
      bfr[fj] = *(const short8*)(Bs + p * 128 + (cp << 4));
    }
#pragma unroll
    for (int f = 0; f < 2; ++f)
#pragma unroll
      for (int fj = 0; fj < 4; ++fj)
        acc[f][fj] = __builtin_amdgcn_mfma_f32_16x16x32_bf16(af[f], bfr[fj], acc[f][fj], 0, 0, 0);

    // xb write: wave w covers tiles t%4==w (full 32x32-f32 tile per wave)
    if (((t ^ wave) & 3) == 0) {
#pragma unroll
      for (int f = 0; f < 2; ++f) {
        const int row = f * 16 + lr;
        *(short8*)(xbB + (size_t)(m0 + row) * 2048 + (size_t)t * 64 + lk * 16) = af[f];
      }
    }

    if (t < 31) {
      if (t < 29)       { VMC(10); }  // drain st(t+1); never needs store acks
      else if (t == 29) { VMC(5); }   // st(32) was nop: newer loads = st(31)=5
      else              { VMC(0); }   // t==30: drain st(31) (+ stores, tail)
      __builtin_amdgcn_s_barrier();
    }
  }

  // epilogue: G = acc*C2 + bb2
#pragma unroll
  for (int f = 0; f < 2; ++f)
#pragma unroll
    for (int fj = 0; fj < 4; ++fj)
#pragma unroll
      for (int j = 0; j < 4; ++j) {
        const int rg = m0 + f * 16 + lk * 4 + j;
        const int cg = wave * 64 + fj * 16 + lr;
        G[(size_t)rg * STATE + cg] = fmaf(acc[f][fj][j], C2F, bb2[cg]);
      }
}

// ---------------- chunked-parallel scan with warmup ---------------------------
// W=128: contraction |exp(A)(1-s^2)| ~0.85-0.95/step -> warmup error <~1.4e-3.
__global__ __launch_bounds__(256) void scan_kernel(
    const float* __restrict__ G, const float* __restrict__ mP2arr,
    unsigned short* __restrict__ states) {
  const int b = blockIdx.x >> 6;
  const int chunk = blockIdx.x & 63;
  const int n = threadIdx.x;
  const int t0 = chunk * 64;
  const int start = (t0 > 128) ? (t0 - 128) : 0;
  const int nw = t0 - start;
  const int total = nw + 64;

  const float* g = G + ((size_t)b * SEQ + start) * STATE + n;
  unsigned short* q = states + ((size_t)b * SEQ + start) * STATE + n;
  const float mP2 = mP2arr[n];

  float r = 0.5f;
  constexpr int CH = 16;
  float cur[CH], nxt[CH];
#pragma unroll
  for (int j = 0; j < CH; ++j) cur[j] = g[(size_t)j * STATE];

  const int NC = total / CH;
  for (int c = 0; c < NC; ++c) {
    if (c + 1 < NC) {
      const float* pn = g + (size_t)(c + 1) * CH * STATE;
#pragma unroll
      for (int j = 0; j < CH; ++j) nxt[j] = pn[(size_t)j * STATE];
    }
    if (c * CH >= nw) {
      unsigned short* qc = q + (size_t)c * CH * STATE;
#pragma unroll
      for (int j = 0; j < CH; ++j) {
        const float t = fmaf(mP2, r, cur[j]);
        const float e = __builtin_amdgcn_exp2f(t);
        r = __builtin_amdgcn_rcpf(1.0f + e);
        const float s = fmaf(-2.0f, r, 1.0f);
        qc[(size_t)j * STATE] = f2bf(s);
      }
    } else {
#pragma unroll
      for (int j = 0; j < CH; ++j) {
        const float t = fmaf(mP2, r, cur[j]);
        const float e = __builtin_amdgcn_exp2f(t);
        r = __builtin_amdgcn_rcpf(1.0f + e);
      }
    }
    if (c + 1 < NC) {
#pragma unroll
      for (int j = 0; j < CH; ++j) cur[j] = nxt[j];
    }
  }
}

// ---------------- gemm_out: dout = [states|x] @ [Cw|Dw]^T + (Cb+Db) ----------
// Round-4/6 8-phase schedule (best measured 49.4us, unchanged). BM=BN=256,
// BK=64, K=1280 (20 tiles, 2/iter). 8 waves (2Mx4N). LDS 128KB dbuf.
#define PH(TILE, Q, STG, VMST)                                                 \
  do {                                                                         \
    const char* As = lds + ((TILE) & 1) * 32768;                               \
    const char* Bs = lds + 65536 + ((TILE) & 1) * 32768;                       \
    if ((Q) == 0) {                                                            \
      _Pragma("unroll") for (int fj = 0; fj < 4; ++fj) {                       \
        const int r = wn * 64 + fj * 16 + lr;                                  \
        _Pragma("unroll") for (int kk = 0; kk < 2; ++kk)                       \
          bfr[fj][kk] = *(const short8*)(Bs + r * 128 +                        \
                                         (((kk * 4 + lk) ^ (r & 7)) << 4));    \
      }                                                                        \
    }                                                                          \
    short8 af[2][2];                                                           \
    _Pragma("unroll") for (int fl = 0; fl < 2; ++fl) {                         \
      const int r = wm * 128 + (Q) * 32 + fl * 16 + lr;                        \
      _Pragma("unroll") for (int kk = 0; kk < 2; ++kk)                         \
        af[fl][kk] = *(const short8*)(As + r * 128 +                           \
                                      (((kk * 4 + lk) ^ (r & 7)) << 4));       \
    }                                                                          \
    STG;                                                                       \
    if ((Q) == 0) asm volatile("s_waitcnt lgkmcnt(8)" ::: "memory");           \
    __builtin_amdgcn_s_barrier();                                              \
    __builtin_amdgcn_s_setprio(1);                                             \
    _Pragma("unroll") for (int kk = 0; kk < 2; ++kk)                           \
      _Pragma("unroll") for (int fl = 0; fl < 2; ++fl)                         \
        _Pragma("unroll") for (int fj = 0; fj < 4; ++fj)                       \
          acc[(Q) * 2 + fl][fj] = __builtin_amdgcn_mfma_f32_16x16x32_bf16(     \
              af[fl][kk], bfr[fj][kk], acc[(Q) * 2 + fl][fj], 0, 0, 0);        \
    __builtin_amdgcn_s_setprio(0);                                             \
    VMST;                                                                      \
    __builtin_amdgcn_s_barrier();                                              \
  } while (0)

__global__ __launch_bounds__(512, 2) void gemm_out(
    const unsigned short* __restrict__ stb,  // [16384][256] bf16
    const unsigned short* __restrict__ xb,   // [16384][1024] bf16
    const unsigned short* __restrict__ wob,  // [1024][1280] bf16
    const float* __restrict__ cbdb,          // [1024]
    float* __restrict__ dout)                // [16384][1024] f32
{
  __shared__ char lds[131072];  // A: 2x32KB @0, B: 2x32KB @65536

  const int tid = threadIdx.x;
  const int wave = tid >> 6;
  const int lane = tid & 63;
  const int lr = lane & 15;
  const int lk = lane >> 4;
  const int wm = wave >> 2;  // 0..1
  const int wn = wave & 3;   // 0..3

  const int bs = ((blockIdx.x & 7) << 5) | (blockIdx.x >> 3);  // XCD swizzle (256%8==0)
  const int m0 = (bs >> 2) * 256;
  const int n0 = (bs & 3) * 256;

  const char* stbB = (const char*)stb;
  const char* xbB  = (const char*)xb;
  const char* wobB = (const char*)wob;

  f32x4 acc[8][4];
#pragma unroll
  for (int i = 0; i < 8; ++i)
#pragma unroll
    for (int j = 0; j < 4; ++j) acc[i][j] = (f32x4){0.f, 0.f, 0.f, 0.f};

  // stage one half-tile (128 rows x 64 cols bf16 = 16KB = 2 gload_lds/thread)
  auto stageA = [&](int kt, int h) {
    if (kt >= 20) return;
    const char* base;
    size_t str;
    size_t colb;
    if (kt < 4) { base = stbB; str = 512;  colb = (size_t)kt * 128; }
    else        { base = xbB;  str = 2048; colb = (size_t)(kt - 4) * 128; }
    base += (size_t)m0 * str;
#pragma unroll
    for (int i2 = 0; i2 < 2; ++i2) {
      const int s = i2 * 512 + tid;
      const int r = s >> 3;                    // 0..127 within half
      const int cl = (s & 7) ^ (r & 7);        // inverse-swizzled source chunk
      gl_lds16(base + (size_t)(h * 128 + r) * str + colb + cl * 16,
               lds + ((kt & 1) * 32768) + h * 16384 + i2 * 8192 + wave * 1024);
    }
  };
  auto stageB = [&](int kt, int h) {
    if (kt >= 20) return;
#pragma unroll
    for (int i2 = 0; i2 < 2; ++i2) {
      const int s = i2 * 512 + tid;
      const int r = s >> 3;
      const int cl = (s & 7) ^ (r & 7);
      gl_lds16(wobB + (size_t)(n0 + h * 128 + r) * 2560 + (size_t)kt * 128 + cl * 16,
               lds + 65536 + ((kt & 1) * 32768) + h * 16384 + i2 * 8192 + wave * 1024);
    }
  };

  // ---- prologue: A(0), B(0), B(1) = 6 half-tiles (12 loads/wave) ----
  stageA(0, 0); stageA(0, 1);
  stageB(0, 0); stageB(0, 1);
  stageB(1, 0); stageB(1, 1);
  VMC(4);  // A(0),B(0) complete; B(1)'s 4 loads may fly
  __builtin_amdgcn_s_barrier();

  short8 bfr[4][2];
  for (int i = 0; i < 10; ++i) {
    const int e = 2 * i, o = e + 1;
    PH(e, 0, stageA(o, 0), );
    PH(e, 1, stageA(o, 1), );
    PH(e, 2, stageB(e + 2, 0), );
    PH(e, 3, stageB(e + 2, 1), if (i == 9) { VMC(0); } else { VMC(4); });
    PH(o, 0, stageA(e + 2, 0), );
    PH(o, 1, stageA(e + 2, 1), );
    PH(o, 2, stageB(o + 2, 0), );
    PH(o, 3, stageB(o + 2, 1), VMC(4));
  }

  // ---- epilogue: dout = acc + (Cb+Db) ----
#pragma unroll
  for (int fj = 0; fj < 4; ++fj) {
    const int col = n0 + wn * 64 + fj * 16 + lr;
    const float cb = cbdb[col];
#pragma unroll
    for (int m = 0; m < 8; ++m) {
      const int rowb = m0 + wm * 128 + m * 16 + lk * 4;
#pragma unroll
      for (int j = 0; j < 4; ++j)
        dout[(size_t)(rowb + j) * DIM + col] = acc[m][fj][j] + cb;
    }
  }
}

extern "C" void kernel_launch(void* const* d_in, const int* in_sizes, int n_in,
                              void* d_out, int out_size, void* d_ws, size_t ws_size,
                              hipStream_t stream) {
  const float* x  = (const float*)d_in[0];
  const float* A  = (const float*)d_in[1];
  const float* Bw = (const float*)d_in[2];
  const float* Bb = (const float*)d_in[3];
  const float* Cw = (const float*)d_in[4];
  const float* Cb = (const float*)d_in[5];
  const float* Dw = (const float*)d_in[6];
  const float* Db = (const float*)d_in[7];
  float* dout = (float*)d_out;

  char* ws = (char*)d_ws;
  unsigned short* xb   = (unsigned short*)(ws);              // 33,554,432 B
  unsigned short* bwb  = (unsigned short*)(ws + 33554432);   //    524,288 B
  unsigned short* wob  = (unsigned short*)(ws + 34078720);   //  2,621,440 B
  float*          G    = (float*)         (ws + 36700160);   // 16,777,216 B
  unsigned short* stb  = (unsigned short*)(ws + 53477376);   //  8,388,608 B
  float*          bb2  = (float*)         (ws + 61865984);   //      1,024 B
  float*          mP2  = (float*)         (ws + 61867008);   //      1,024 B
  float*          cbdb = (float*)         (ws + 61868032);   //      4,096 B -> 61,872,128

  // 1) weight conversion + constants (tiny)
  convert_w<<<256 + 1024 + 1, 256, 0, stream>>>(
      A, Bw, Bb, Cw, Cb, Dw, Db, bwb, wob, bb2, mP2, cbdb);
  // 2) fused: G = (x @ Bw^T)*C2 + bb2 ; xb = bf16(x)  [BW-rider v3]
  gemm_GX<<<512, 256, 0, stream>>>(x, bwb, G, bb2, xb);
  // 3) chunked recurrent scan -> states (bf16)
  scan_kernel<<<BATCH * 64, 256, 0, stream>>>(G, mP2, stb);
  // 4) dout = [states|x] @ [Cw|Dw]^T + (Cb+Db)
  gemm_out<<<256, 512, 0, stream>>>(stb, xb, wob, cbdb, dout);
}